// Round 11
// baseline (91.148 us; speedup 1.0000x reference)
//
#include <hip/hip_runtime.h>

#define I_FEAT 256
#define O_FEAT 512
#define NSEG   8
#define KDIM   (I_FEAT * NSEG)   // 2048
#define KTOT   (2 * KDIM)        // 4096 (A-part || bias-part)
#define KC_N   (KTOT / 32)       // 128 K32-chunks

typedef _Float16 half8   __attribute__((ext_vector_type(8)));
typedef float    floatx4 __attribute__((ext_vector_type(4)));
typedef uint32_t uintx4  __attribute__((ext_vector_type(4)));

// ---------------- Kernel 1: prep (pack_bfrag ∪ fused LN->Am), bid-split ----------------
__global__ __launch_bounds__(256) void prep(
    const float* __restrict__ x,
    const float* __restrict__ Aw,
    const float* __restrict__ Bw,
    const float* __restrict__ gamma,
    const float* __restrict__ beta,
    uint4* __restrict__ Bf,
    uint2* __restrict__ Am,
    int Bn, int pbTot)
{
    __shared__ uint32_t smem[16 * 260];   // 16640 B, reused by both paths
    const int t   = threadIdx.x;
    const int bid = blockIdx.x;

    if (bid < pbTot) {
        // ---- weight pack path: one 64n x 64k tile -> B-fragment stream ----
        unsigned short (*T)[72] = (unsigned short(*)[72])smem;  // [n][k] f16
        const int n0 = (bid & 7) * 64;
        const int k0 = (bid >> 3) * 64;
        const float* src = (k0 < KDIM) ? (Aw + (size_t)k0 * O_FEAT)
                                       : (Bw + (size_t)(k0 - KDIM) * O_FEAT);
        #pragma unroll
        for (int s = 0; s < 4; ++s) {
            int e  = s * 1024 + t * 4;
            int kl = e >> 6, nl = e & 63;
            const float4 v = *(const float4*)(src + (size_t)kl * O_FEAT + n0 + nl);
            T[nl + 0][kl] = __builtin_bit_cast(unsigned short, (_Float16)v.x);
            T[nl + 1][kl] = __builtin_bit_cast(unsigned short, (_Float16)v.y);
            T[nl + 2][kl] = __builtin_bit_cast(unsigned short, (_Float16)v.z);
            T[nl + 3][kl] = __builtin_bit_cast(unsigned short, (_Float16)v.w);
        }
        __syncthreads();

        const int lane = t & 63, lane16 = lane & 15, quad = lane >> 4;
        const int sub  = t >> 6;
        #pragma unroll
        for (int f = 0; f < 2; ++f) {
            const int combo = sub * 2 + f;       // 0..7
            const int n16g  = combo & 3;
            const int kch   = combo >> 2;
            const int nl = n16g * 16 + lane16;
            const int kl = kch * 32 + quad * 8;
            const uint4 val = *(const uint4*)&T[nl][kl];
            const int n16t = (n0 >> 4) + n16g;
            const int kc   = (k0 >> 5) + kch;
            Bf[((size_t)n16t * KC_N + kc) * 64 + lane] = val;
        }
    } else {
        // ---- LN -> Am path: one mt16 (16 rows), 16 threads per row ----
        uint32_t (*M)[260] = (uint32_t(*)[260])smem;   // [row][feat]
        const int mt16 = bid - pbTot;
        const int rr   = t >> 4;
        const int c16  = t & 15;
        const int row  = mt16 * 16 + rr;
        const bool ok  = (row < Bn);

        float4 v[4];
        const float* xr = x + (size_t)row * I_FEAT + c16 * 16;
        #pragma unroll
        for (int j = 0; j < 4; ++j)
            v[j] = ok ? *(const float4*)(xr + j * 4) : make_float4(0.f, 0.f, 0.f, 0.f);

        float sum = 0.f, sq = 0.f;
        #pragma unroll
        for (int j = 0; j < 4; ++j) {
            sum += v[j].x + v[j].y + v[j].z + v[j].w;
            sq  += v[j].x * v[j].x + v[j].y * v[j].y
                 + v[j].z * v[j].z + v[j].w * v[j].w;
        }
        #pragma unroll
        for (int mask = 1; mask < 16; mask <<= 1) {
            sum += __shfl_xor(sum, mask);
            sq  += __shfl_xor(sq,  mask);
        }
        const float mu  = sum * (1.0f / I_FEAT);
        const float var = sq * (1.0f / I_FEAT) - mu * mu;
        const float rs  = rsqrtf(var + 1e-5f);

        #pragma unroll
        for (int j = 0; j < 4; ++j) {
            const float4 g4 = *(const float4*)(gamma + c16 * 16 + j * 4);
            const float4 b4 = *(const float4*)(beta  + c16 * 16 + j * 4);
            const float vv[4] = { v[j].x, v[j].y, v[j].z, v[j].w };
            const float gg[4] = { g4.x, g4.y, g4.z, g4.w };
            const float bb[4] = { b4.x, b4.y, b4.z, b4.w };
            #pragma unroll
            for (int e = 0; e < 4; ++e) {
                const int c = c16 * 16 + j * 4 + e;
                float xn = (vv[e] - mu) * rs * gg[e] + bb[e];
                float fi = (xn + 1.0f) * 4.0f;   // (xn - GRID_MIN)/STEP, exact fp32
                int seg = (int)fi;                // trunc == jnp astype(int32)
                seg = seg < 0 ? 0 : (seg > NSEG - 1 ? NSEG - 1 : seg);
                _Float16 hx = (_Float16)xn;
                M[rr][c] = ((uint32_t)seg << 16)
                         | (uint32_t)__builtin_bit_cast(unsigned short, hx);
            }
        }
        __syncthreads();

        // emit Am: word(m,w): w<256 -> meta; w>=256 -> (seg<<16 | f16(1.0))
        const int lane = t & 63, g = t >> 6;
        const int m_local = lane & 15, quad = lane >> 4;
        uint2* dst = Am + (size_t)mt16 * 64 * 64 + lane;
        #pragma unroll
        for (int kk = 0; kk < 16; ++kk) {
            const int kcp = g * 16 + kk;
            const int w0  = kcp * 8 + quad;
            const int w1  = w0 + 4;
            const uint32_t u0 = M[m_local][w0 & 255];
            const uint32_t u1 = M[m_local][w1 & 255];
            const uint32_t a  = (w0 >> 8) ? ((u0 & 0xFFFF0000u) | 0x3C00u) : u0;
            const uint32_t b  = (w1 >> 8) ? ((u1 & 0xFFFF0000u) | 0x3C00u) : u1;
            dst[(size_t)kcp * 64] = make_uint2(a, b);
        }
    }
}

// ---------------- Kernel 2: k-split streaming MFMA GEMM ----------------
// Tile 128m x 64n x 1024k per block; grid = 8(ot) x rt128Tot x 4(kh) = 512.
// Streamed bytes: Bf 64 MB + Am 32 MB (was 384 MB at 64x32 tiles) ->
// ~384 KB/CU at ~20 B/cyc/CU L1-miss streaming => ~8-10 us.
// No LDS, no barriers; partials to P (reduced by kernel 3).
static __device__ __forceinline__ half8 build_onehot(uint32_t u) {
    const uint32_t xb  = u & 0xFFFFu;
    const uint32_t seg = u >> 16;
    const uint64_t oh  = (uint64_t)xb << ((seg & 3u) << 4);
    const uint64_t lo  = (seg < 4u) ? oh : 0ull;
    const uint64_t hi  = (seg < 4u) ? 0ull : oh;
    uintx4 w;
    w[0] = (uint32_t)lo; w[1] = (uint32_t)(lo >> 32);
    w[2] = (uint32_t)hi; w[3] = (uint32_t)(hi >> 32);
    return __builtin_bit_cast(half8, w);
}

__global__ __launch_bounds__(256, 2) void kan_gemm(
    const uint2* __restrict__ Am,
    const uint4* __restrict__ Bf,
    float* __restrict__ P,
    int rt128Tot)
{
    const int t      = threadIdx.x;
    const int wave   = t >> 6, lane = t & 63;
    const int lane16 = lane & 15, quad = lane >> 4;

    const int bid = blockIdx.x;
    const int ot  = bid & 7;                 // XCD = bid%8 = ot -> 512 KB Bf slice L2-resident
    const int rem = bid >> 3;
    const int rt  = rem % rt128Tot;
    const int kh  = rem / rt128Tot;          // k-quarter (kc in [kh*32, kh*32+32))

    // A-meta streams: block rows = rt*128 .. +127; wave owns 32 rows = 2 mt16
    const uint2* pa0 = Am + ((size_t)(rt * 8 + wave * 2 + 0) * 64) * 64 + lane;
    const uint2* pa1 = Am + ((size_t)(rt * 8 + wave * 2 + 1) * 64) * 64 + lane;
    // B-fragment streams: 4 n16 tiles = 64 cols
    const uint4* pb0 = Bf + ((size_t)(ot * 4 + 0) * KC_N) * 64 + lane;
    const uint4* pb1 = Bf + ((size_t)(ot * 4 + 1) * KC_N) * 64 + lane;
    const uint4* pb2 = Bf + ((size_t)(ot * 4 + 2) * KC_N) * 64 + lane;
    const uint4* pb3 = Bf + ((size_t)(ot * 4 + 3) * KC_N) * 64 + lane;

    floatx4 acc[2][4] = {};
    const int kcp0 = kh * 16;

    #pragma unroll 4
    for (int p = 0; p < 16; ++p) {
        const int kcp = kcp0 + p;
        const uint2 u0 = pa0[(size_t)kcp * 64];
        const uint2 u1 = pa1[(size_t)kcp * 64];
        const size_t o0 = (size_t)(2 * kcp) * 64;
        const size_t o1 = o0 + 64;
        const uint4 bv00 = pb0[o0], bv01 = pb0[o1];
        const uint4 bv10 = pb1[o0], bv11 = pb1[o1];
        const uint4 bv20 = pb2[o0], bv21 = pb2[o1];
        const uint4 bv30 = pb3[o0], bv31 = pb3[o1];
        {   // kc = 2*kcp
            const half8 a0 = build_onehot(u0.x);
            const half8 a1 = build_onehot(u1.x);
            const half8 n0 = __builtin_bit_cast(half8, bv00);
            const half8 n1 = __builtin_bit_cast(half8, bv10);
            const half8 n2 = __builtin_bit_cast(half8, bv20);
            const half8 n3 = __builtin_bit_cast(half8, bv30);
            acc[0][0] = __builtin_amdgcn_mfma_f32_16x16x32_f16(a0, n0, acc[0][0], 0, 0, 0);
            acc[0][1] = __builtin_amdgcn_mfma_f32_16x16x32_f16(a0, n1, acc[0][1], 0, 0, 0);
            acc[0][2] = __builtin_amdgcn_mfma_f32_16x16x32_f16(a0, n2, acc[0][2], 0, 0, 0);
            acc[0][3] = __builtin_amdgcn_mfma_f32_16x16x32_f16(a0, n3, acc[0][3], 0, 0, 0);
            acc[1][0] = __builtin_amdgcn_mfma_f32_16x16x32_f16(a1, n0, acc[1][0], 0, 0, 0);
            acc[1][1] = __builtin_amdgcn_mfma_f32_16x16x32_f16(a1, n1, acc[1][1], 0, 0, 0);
            acc[1][2] = __builtin_amdgcn_mfma_f32_16x16x32_f16(a1, n2, acc[1][2], 0, 0, 0);
            acc[1][3] = __builtin_amdgcn_mfma_f32_16x16x32_f16(a1, n3, acc[1][3], 0, 0, 0);
        }
        {   // kc = 2*kcp + 1
            const half8 a0 = build_onehot(u0.y);
            const half8 a1 = build_onehot(u1.y);
            const half8 n0 = __builtin_bit_cast(half8, bv01);
            const half8 n1 = __builtin_bit_cast(half8, bv11);
            const half8 n2 = __builtin_bit_cast(half8, bv21);
            const half8 n3 = __builtin_bit_cast(half8, bv31);
            acc[0][0] = __builtin_amdgcn_mfma_f32_16x16x32_f16(a0, n0, acc[0][0], 0, 0, 0);
            acc[0][1] = __builtin_amdgcn_mfma_f32_16x16x32_f16(a0, n1, acc[0][1], 0, 0, 0);
            acc[0][2] = __builtin_amdgcn_mfma_f32_16x16x32_f16(a0, n2, acc[0][2], 0, 0, 0);
            acc[0][3] = __builtin_amdgcn_mfma_f32_16x16x32_f16(a0, n3, acc[0][3], 0, 0, 0);
            acc[1][0] = __builtin_amdgcn_mfma_f32_16x16x32_f16(a1, n0, acc[1][0], 0, 0, 0);
            acc[1][1] = __builtin_amdgcn_mfma_f32_16x16x32_f16(a1, n1, acc[1][1], 0, 0, 0);
            acc[1][2] = __builtin_amdgcn_mfma_f32_16x16x32_f16(a1, n2, acc[1][2], 0, 0, 0);
            acc[1][3] = __builtin_amdgcn_mfma_f32_16x16x32_f16(a1, n3, acc[1][3], 0, 0, 0);
        }
    }

    // epilogue: partial tile to P[bid] (C/D layout col=lane&15, row=quad*4+reg)
    float* pblk = P + (size_t)bid * (128 * 64);
    #pragma unroll
    for (int sm = 0; sm < 2; ++sm) {
        const int ml0 = wave * 32 + sm * 16 + quad * 4;
        #pragma unroll
        for (int j = 0; j < 4; ++j) {
            const int nl = j * 16 + lane16;
            #pragma unroll
            for (int r = 0; r < 4; ++r)
                pblk[(ml0 + r) * 64 + nl] = acc[sm][j][r];
        }
    }
}

// ---------------- Kernel 3: 4-way k-partial reduction ----------------
__global__ __launch_bounds__(256) void reduceP(
    const float* __restrict__ P,
    float* __restrict__ out,
    int Bn, int rt128Tot)
{
    const int gid = blockIdx.x * 256 + threadIdx.x;
    const int e0  = gid * 4;
    const int m   = e0 >> 9;          // /512
    const int n   = e0 & 511;
    if (m >= Bn) return;
    const int rt = m >> 7, ml = m & 127;
    const int ot = n >> 6, nl = n & 63;
    const size_t base     = ((size_t)(rt * 8 + ot)) * 8192 + ml * 64 + nl;
    const size_t khStride = (size_t)rt128Tot * 8 * 8192;

    const float4 p0 = *(const float4*)(P + base);
    const float4 p1 = *(const float4*)(P + base + khStride);
    const float4 p2 = *(const float4*)(P + base + 2 * khStride);
    const float4 p3 = *(const float4*)(P + base + 3 * khStride);
    float4 s;
    s.x = (p0.x + p1.x) + (p2.x + p3.x);
    s.y = (p0.y + p1.y) + (p2.y + p3.y);
    s.z = (p0.z + p1.z) + (p2.z + p3.z);
    s.w = (p0.w + p1.w) + (p2.w + p3.w);
    *(float4*)(out + e0) = s;
}

extern "C" void kernel_launch(void* const* d_in, const int* in_sizes, int n_in,
                              void* d_out, int out_size, void* d_ws, size_t ws_size,
                              hipStream_t stream) {
    const float* x   = (const float*)d_in[0];
    const float* Aw  = (const float*)d_in[1];
    const float* Bw  = (const float*)d_in[2];
    const float* gam = (const float*)d_in[3];
    const float* bet = (const float*)d_in[4];
    float* out       = (float*)d_out;

    const int Bn       = in_sizes[0] / I_FEAT;
    const int mt16Tot  = (Bn + 15) / 16;
    const int rt128Tot = (Bn + 127) / 128;
    const int pbTot    = (O_FEAT / 64) * (KTOT / 64);   // 512

    // ws: Bf 4MB | Am (mt16Tot*64*64*8B = 4MB) | P (4*rt128Tot*8*32KB = 16MB)
    uint4* Bf = (uint4*)d_ws;
    uint2* Am = (uint2*)(Bf + (size_t)(O_FEAT / 16) * KC_N * 64);
    float* P  = (float*)(Am + (size_t)mt16Tot * 64 * 64);

    hipLaunchKernelGGL(prep, dim3(pbTot + mt16Tot), dim3(256), 0, stream,
                       x, Aw, Bw, gam, bet, Bf, Am, Bn, pbTot);
    hipLaunchKernelGGL(kan_gemm, dim3(8 * rt128Tot * 4), dim3(256), 0, stream,
                       Am, Bf, P, rt128Tot);
    hipLaunchKernelGGL(reduceP, dim3((Bn * O_FEAT / 4 + 255) / 256), dim3(256), 0, stream,
                       P, out, Bn, rt128Tot);
}